// Round 1
// baseline (9.546 us; speedup 1.0000x reference)
//
#include <hip/hip_runtime.h>

// SE(3) exponential from two tiny MLPs, applied to a 4x4 matrix.
// Single block, single wave (64 lanes). Each lane handles 8 of the 512
// hidden units for BOTH MLPs, accumulating 6 partial dot products
// (w0,w1,w2, v0,v1,v2). Butterfly __shfl_xor reduction gives every lane
// the full sums; all lanes redundantly compute the 3x3 Rodrigues math;
// lanes 0..15 each write one element of exp_i @ x.
__global__ __launch_bounds__(64)
void se3_mlp_kernel(const float* __restrict__ x,      // (4,4)
                    const float* __restrict__ t,      // (1,)
                    const float* __restrict__ W1,     // (512,1)
                    const float* __restrict__ Wb1,    // (512,)
                    const float* __restrict__ W2,     // (3,512)
                    const float* __restrict__ Wb2,    // (3,)
                    const float* __restrict__ V1,     // (512,1)
                    const float* __restrict__ Vb1,    // (512,)
                    const float* __restrict__ V2,     // (3,512)
                    const float* __restrict__ Vb2,    // (3,)
                    const float* __restrict__ theta_p,// scalar
                    float* __restrict__ out)          // (4,4)
{
    const int lane = threadIdx.x;          // 0..63
    const int base = lane * 8;             // this lane's 8 hidden units
    const float tv = t[0];

    float w0 = 0.f, w1 = 0.f, w2 = 0.f;    // W-MLP partial outputs
    float v0 = 0.f, v1 = 0.f, v2 = 0.f;    // V-MLP partial outputs

    // ---- W-MLP: h = relu(W1*t + Wb1); partial w_j = sum W2[j][i]*h[i] ----
    {
        float h[8];
        #pragma unroll
        for (int q = 0; q < 2; ++q) {
            float4 a = *(const float4*)(W1  + base + q * 4);
            float4 b = *(const float4*)(Wb1 + base + q * 4);
            h[q*4+0] = fmaxf(0.f, fmaf(a.x, tv, b.x));
            h[q*4+1] = fmaxf(0.f, fmaf(a.y, tv, b.y));
            h[q*4+2] = fmaxf(0.f, fmaf(a.z, tv, b.z));
            h[q*4+3] = fmaxf(0.f, fmaf(a.w, tv, b.w));
        }
        #pragma unroll
        for (int j = 0; j < 3; ++j) {
            float acc = 0.f;
            #pragma unroll
            for (int q = 0; q < 2; ++q) {
                float4 r = *(const float4*)(W2 + j * 512 + base + q * 4);
                acc = fmaf(r.x, h[q*4+0], acc);
                acc = fmaf(r.y, h[q*4+1], acc);
                acc = fmaf(r.z, h[q*4+2], acc);
                acc = fmaf(r.w, h[q*4+3], acc);
            }
            if (j == 0) w0 = acc; else if (j == 1) w1 = acc; else w2 = acc;
        }
    }

    // ---- V-MLP: same structure ----
    {
        float h[8];
        #pragma unroll
        for (int q = 0; q < 2; ++q) {
            float4 a = *(const float4*)(V1  + base + q * 4);
            float4 b = *(const float4*)(Vb1 + base + q * 4);
            h[q*4+0] = fmaxf(0.f, fmaf(a.x, tv, b.x));
            h[q*4+1] = fmaxf(0.f, fmaf(a.y, tv, b.y));
            h[q*4+2] = fmaxf(0.f, fmaf(a.z, tv, b.z));
            h[q*4+3] = fmaxf(0.f, fmaf(a.w, tv, b.w));
        }
        #pragma unroll
        for (int j = 0; j < 3; ++j) {
            float acc = 0.f;
            #pragma unroll
            for (int q = 0; q < 2; ++q) {
                float4 r = *(const float4*)(V2 + j * 512 + base + q * 4);
                acc = fmaf(r.x, h[q*4+0], acc);
                acc = fmaf(r.y, h[q*4+1], acc);
                acc = fmaf(r.z, h[q*4+2], acc);
                acc = fmaf(r.w, h[q*4+3], acc);
            }
            if (j == 0) v0 = acc; else if (j == 1) v1 = acc; else v2 = acc;
        }
    }

    // ---- butterfly reduction across the 64-lane wave (all lanes get sums) --
    #pragma unroll
    for (int off = 32; off > 0; off >>= 1) {
        w0 += __shfl_xor(w0, off);
        w1 += __shfl_xor(w1, off);
        w2 += __shfl_xor(w2, off);
        v0 += __shfl_xor(v0, off);
        v1 += __shfl_xor(v1, off);
        v2 += __shfl_xor(v2, off);
    }

    // ---- add output biases ----
    w0 += Wb2[0]; w1 += Wb2[1]; w2 += Wb2[2];
    v0 += Vb2[0]; v1 += Vb2[1]; v2 += Vb2[2];

    // ---- Rodrigues / SE(3) exponential (all lanes, redundant) ----
    const float th = theta_p[0];
    const float s  = sinf(th);
    const float c  = cosf(th);
    const float omc = 1.f - c;   // 1 - cos
    const float tms = th - s;    // theta - sin

    // ss (skew) and ss2 = ss @ ss, explicit:
    // ss = [  0  -w2   w1 ]
    //      [ w2    0  -w0 ]
    //      [-w1   w0    0 ]
    float ss[3][3]  = {{0.f, -w2,  w1},
                       { w2, 0.f, -w0},
                       {-w1,  w0, 0.f}};
    float ss2[3][3];
    ss2[0][0] = -(w1*w1 + w2*w2);
    ss2[0][1] =   w0*w1;
    ss2[0][2] =   w0*w2;
    ss2[1][0] =   w0*w1;
    ss2[1][1] = -(w0*w0 + w2*w2);
    ss2[1][2] =   w1*w2;
    ss2[2][0] =   w0*w2;
    ss2[2][1] =   w1*w2;
    ss2[2][2] = -(w0*w0 + w1*w1);

    float R[3][3], Vm[3][3];
    #pragma unroll
    for (int i = 0; i < 3; ++i) {
        #pragma unroll
        for (int j = 0; j < 3; ++j) {
            const float eye = (i == j) ? 1.f : 0.f;
            R[i][j]  = eye + s * ss[i][j] + omc * ss2[i][j];
            Vm[i][j] = th * eye + omc * ss[i][j] + tms * ss2[i][j];
        }
    }
    float trans[3];
    #pragma unroll
    for (int i = 0; i < 3; ++i)
        trans[i] = Vm[i][0] * v0 + Vm[i][1] * v1 + Vm[i][2] * v2;

    // ---- out = exp_i @ x ; lanes 0..15 write one element each ----
    if (lane < 16) {
        const int r = lane >> 2;
        const int col = lane & 3;
        float er0, er1, er2, er3;
        if (r < 3) { er0 = R[r][0]; er1 = R[r][1]; er2 = R[r][2]; er3 = trans[r]; }
        else       { er0 = 0.f;     er1 = 0.f;     er2 = 0.f;     er3 = 1.f; }
        float o = er0 * x[0*4 + col]
                + er1 * x[1*4 + col]
                + er2 * x[2*4 + col]
                + er3 * x[3*4 + col];
        out[r * 4 + col] = o;
    }
}

extern "C" void kernel_launch(void* const* d_in, const int* in_sizes, int n_in,
                              void* d_out, int out_size, void* d_ws, size_t ws_size,
                              hipStream_t stream) {
    const float* x     = (const float*)d_in[0];
    const float* t     = (const float*)d_in[1];
    const float* W1    = (const float*)d_in[2];
    const float* Wb1   = (const float*)d_in[3];
    const float* W2    = (const float*)d_in[4];
    const float* Wb2   = (const float*)d_in[5];
    const float* V1    = (const float*)d_in[6];
    const float* Vb1   = (const float*)d_in[7];
    const float* V2    = (const float*)d_in[8];
    const float* Vb2   = (const float*)d_in[9];
    const float* theta = (const float*)d_in[10];
    float* out = (float*)d_out;

    se3_mlp_kernel<<<1, 64, 0, stream>>>(x, t, W1, Wb1, W2, Wb2,
                                         V1, Vb1, V2, Vb2, theta, out);
}